// Round 1
// baseline (2014.843 us; speedup 1.0000x reference)
//
#include <hip/hip_runtime.h>

#define S_ 2048
#define D_ 1024
#define H_ 16
#define HD_ 64

// ---------------- GEMM: C[M,N] = A[M,K] @ W[K,N] + bias ----------------
// 128x128 tile, BK=16, 256 threads, 8x8 accum per thread.
// mode 0: plain store to outp. mode 1: scatter qkv -> q/k/v [B,H,S,HD].
__global__ __launch_bounds__(256) void gemm128(
    const float* __restrict__ A, const float* __restrict__ W,
    const float* __restrict__ bias, float* __restrict__ outp,
    float* __restrict__ qw, float* __restrict__ kw, float* __restrict__ vw,
    int M, int N, int K, int mode)
{
    __shared__ float As[16][132];  // [k][m] transposed, padded (+4)
    __shared__ float Bs[16][128];  // [k][n]

    const int tid = threadIdx.x;
    const int tx = tid & 15;
    const int ty = tid >> 4;
    const int row0 = blockIdx.y * 128;
    const int col0 = blockIdx.x * 128;

    float acc[8][8];
#pragma unroll
    for (int i = 0; i < 8; ++i)
#pragma unroll
        for (int j = 0; j < 8; ++j) acc[i][j] = 0.0f;

    const int ar = tid >> 2;          // 0..63
    const int ac4 = (tid & 3) << 2;   // 0,4,8,12
    const int br = tid >> 5;          // 0..7
    const int bc4 = (tid & 31) << 2;  // 0..124

    for (int k0 = 0; k0 < K; k0 += 16) {
#pragma unroll
        for (int p = 0; p < 2; ++p) {
            const int r = ar + p * 64;
            const float4 av = *(const float4*)&A[(size_t)(row0 + r) * K + k0 + ac4];
            As[ac4 + 0][r] = av.x;
            As[ac4 + 1][r] = av.y;
            As[ac4 + 2][r] = av.z;
            As[ac4 + 3][r] = av.w;
        }
#pragma unroll
        for (int p = 0; p < 2; ++p) {
            const int r = br + p * 8;
            *(float4*)&Bs[r][bc4] = *(const float4*)&W[(size_t)(k0 + r) * N + col0 + bc4];
        }
        __syncthreads();
#pragma unroll
        for (int kk = 0; kk < 16; ++kk) {
            const float4 a0 = *(const float4*)&As[kk][ty * 4];
            const float4 a1 = *(const float4*)&As[kk][64 + ty * 4];
            const float4 b0 = *(const float4*)&Bs[kk][tx * 4];
            const float4 b1 = *(const float4*)&Bs[kk][64 + tx * 4];
            const float av8[8] = {a0.x, a0.y, a0.z, a0.w, a1.x, a1.y, a1.z, a1.w};
            const float bv8[8] = {b0.x, b0.y, b0.z, b0.w, b1.x, b1.y, b1.z, b1.w};
#pragma unroll
            for (int i = 0; i < 8; ++i)
#pragma unroll
                for (int j = 0; j < 8; ++j)
                    acc[i][j] += av8[i] * bv8[j];
        }
        __syncthreads();
    }

#pragma unroll
    for (int ii = 0; ii < 2; ++ii)
#pragma unroll
        for (int i = 0; i < 4; ++i) {
            const int row = row0 + ii * 64 + ty * 4 + i;
#pragma unroll
            for (int jj = 0; jj < 2; ++jj) {
                const int colb = col0 + jj * 64 + tx * 4;
                const float4 b4 = *(const float4*)&bias[colb];
                float4 r4;
                r4.x = acc[ii * 4 + i][jj * 4 + 0] + b4.x;
                r4.y = acc[ii * 4 + i][jj * 4 + 1] + b4.y;
                r4.z = acc[ii * 4 + i][jj * 4 + 2] + b4.z;
                r4.w = acc[ii * 4 + i][jj * 4 + 3] + b4.w;
                if (mode == 0) {
                    *(float4*)&outp[(size_t)row * N + colb] = r4;
                } else {
                    const int region = colb >> 10;       // 0:q 1:k 2:v (block never straddles)
                    const int h = (colb & 1023) >> 6;
                    const int d0 = colb & 63;
                    const int b = row >> 11;
                    const int s = row & 2047;
                    float* dst = (region == 0) ? qw : (region == 1) ? kw : vw;
                    *(float4*)&dst[((size_t)(b * H_ + h) * S_ + s) * HD_ + d0] = r4;
                }
            }
        }
}

// ---------------- Attention: per-(b,h,64-row Q tile) block ----------------
// Phase 1: online softmax stats (per-thread partials + shuffle reduce).
// Phase 2: recompute scores, write normalized attn, accumulate ctx = P@V.
__global__ __launch_bounds__(256) void attn_kernel(
    const float* __restrict__ qg, const float* __restrict__ kg,
    const float* __restrict__ vg, const float* __restrict__ mask,
    float* __restrict__ attnOut, float* __restrict__ ctxOut)
{
    __shared__ float Qs[64][68];
    __shared__ float KPs[64][68];   // K tile; reused as P tile in phase 2
    __shared__ float VsT[64][68];   // V transposed [d][key]
    __shared__ float mS[64], lS[64], maskS[64];

    const int tid = threadIdx.x;
    const int tx = tid & 15;
    const int ty = tid >> 4;
    const int qt = blockIdx.x & 31;
    const int bh = blockIdx.x >> 5;
    const int b = bh >> 4;
    const int h = bh & 15;
    const size_t base = (size_t)bh * S_ * HD_;

    const int lr = tid >> 4;          // 0..15 (tile row group for staging)
    const int lc4 = (tid & 15) * 4;   // 0..60

    // load Q tile
#pragma unroll
    for (int p = 0; p < 4; ++p) {
        const int rr = lr + p * 16;
        *(float4*)&Qs[rr][lc4] =
            *(const float4*)&qg[base + (size_t)(qt * 64 + rr) * HD_ + lc4];
    }

    float m_i[4], l_i[4];
#pragma unroll
    for (int i = 0; i < 4; ++i) { m_i[i] = -1e30f; l_i[i] = 0.0f; }
    __syncthreads();

    // ---- phase 1: softmax stats ----
    for (int jt = 0; jt <= qt; ++jt) {
#pragma unroll
        for (int p = 0; p < 4; ++p) {
            const int rr = lr + p * 16;
            *(float4*)&KPs[rr][lc4] =
                *(const float4*)&kg[base + (size_t)(jt * 64 + rr) * HD_ + lc4];
        }
        if (tid < 64) maskS[tid] = mask[b * S_ + jt * 64 + tid];
        __syncthreads();

        float s[4][4];
#pragma unroll
        for (int i = 0; i < 4; ++i)
#pragma unroll
            for (int j = 0; j < 4; ++j) s[i][j] = 0.0f;
        for (int d4 = 0; d4 < 64; d4 += 4) {
            float4 qv[4], kv[4];
#pragma unroll
            for (int i = 0; i < 4; ++i) qv[i] = *(const float4*)&Qs[ty + 16 * i][d4];
#pragma unroll
            for (int j = 0; j < 4; ++j) kv[j] = *(const float4*)&KPs[tx + 16 * j][d4];
#pragma unroll
            for (int i = 0; i < 4; ++i)
#pragma unroll
                for (int j = 0; j < 4; ++j)
                    s[i][j] += qv[i].x * kv[j].x + qv[i].y * kv[j].y +
                               qv[i].z * kv[j].z + qv[i].w * kv[j].w;
        }
#pragma unroll
        for (int i = 0; i < 4; ++i) {
            const int q = qt * 64 + ty + 16 * i;
#pragma unroll
            for (int j = 0; j < 4; ++j) {
                const int col = jt * 64 + tx + 16 * j;
                if (col <= q && maskS[tx + 16 * j] == 1.0f) {
                    const float sv = s[i][j] * 0.125f;
                    const float mn = fmaxf(m_i[i], sv);
                    l_i[i] = l_i[i] * __expf(m_i[i] - mn) + __expf(sv - mn);
                    m_i[i] = mn;
                }
            }
        }
        __syncthreads();
    }

    // reduce (m,l) across the 16 lanes sharing each q row
#pragma unroll
    for (int i = 0; i < 4; ++i) {
        float m = m_i[i], l = l_i[i];
#pragma unroll
        for (int off = 1; off < 16; off <<= 1) {
            const float mo = __shfl_xor(m, off, 64);
            const float lo = __shfl_xor(l, off, 64);
            const float mn = fmaxf(m, mo);
            l = l * __expf(m - mn) + lo * __expf(mo - mn);
            m = mn;
        }
        if (tx == 0) { mS[ty + 16 * i] = m; lS[ty + 16 * i] = 1.0f / l; }
    }
    __syncthreads();

    // ---- phase 2: attn write + ctx accumulate ----
    float ctxA[4][4];
#pragma unroll
    for (int i = 0; i < 4; ++i)
#pragma unroll
        for (int j = 0; j < 4; ++j) ctxA[i][j] = 0.0f;

    float* attnBH = attnOut + (size_t)bh * S_ * S_;

    for (int jt = 0; jt < 32; ++jt) {
        if (jt <= qt) {
#pragma unroll
            for (int p = 0; p < 4; ++p) {
                const int rr = lr + p * 16;
                *(float4*)&KPs[rr][lc4] =
                    *(const float4*)&kg[base + (size_t)(jt * 64 + rr) * HD_ + lc4];
                const float4 vv =
                    *(const float4*)&vg[base + (size_t)(jt * 64 + rr) * HD_ + lc4];
                VsT[lc4 + 0][rr] = vv.x;
                VsT[lc4 + 1][rr] = vv.y;
                VsT[lc4 + 2][rr] = vv.z;
                VsT[lc4 + 3][rr] = vv.w;
            }
            if (tid < 64) maskS[tid] = mask[b * S_ + jt * 64 + tid];
            __syncthreads();

            float s[4][4];
#pragma unroll
            for (int i = 0; i < 4; ++i)
#pragma unroll
                for (int j = 0; j < 4; ++j) s[i][j] = 0.0f;
            for (int d4 = 0; d4 < 64; d4 += 4) {
                float4 qv[4], kv[4];
#pragma unroll
                for (int i = 0; i < 4; ++i) qv[i] = *(const float4*)&Qs[ty + 16 * i][d4];
#pragma unroll
                for (int j = 0; j < 4; ++j) kv[j] = *(const float4*)&KPs[tx + 16 * j][d4];
#pragma unroll
                for (int i = 0; i < 4; ++i)
#pragma unroll
                    for (int j = 0; j < 4; ++j)
                        s[i][j] += qv[i].x * kv[j].x + qv[i].y * kv[j].y +
                                   qv[i].z * kv[j].z + qv[i].w * kv[j].w;
            }
            float pr[4][4];
#pragma unroll
            for (int i = 0; i < 4; ++i) {
                const int q = qt * 64 + ty + 16 * i;
                const float mm = mS[ty + 16 * i];
                const float rl = lS[ty + 16 * i];
#pragma unroll
                for (int j = 0; j < 4; ++j) {
                    const int col = jt * 64 + tx + 16 * j;
                    const bool ok = (col <= q) && (maskS[tx + 16 * j] == 1.0f);
                    pr[i][j] = ok ? __expf(s[i][j] * 0.125f - mm) * rl : 0.0f;
                    attnBH[(size_t)q * S_ + col] = pr[i][j];
                }
            }
            __syncthreads();  // everyone done reading KPs as K
#pragma unroll
            for (int i = 0; i < 4; ++i)
#pragma unroll
                for (int j = 0; j < 4; ++j)
                    KPs[ty + 16 * i][tx + 16 * j] = pr[i][j];
            __syncthreads();

            for (int j4 = 0; j4 < 64; j4 += 4) {
                float4 pv[4], vv[4];
#pragma unroll
                for (int i = 0; i < 4; ++i) pv[i] = *(const float4*)&KPs[ty + 16 * i][j4];
#pragma unroll
                for (int j = 0; j < 4; ++j) vv[j] = *(const float4*)&VsT[tx + 16 * j][j4];
#pragma unroll
                for (int i = 0; i < 4; ++i)
#pragma unroll
                    for (int j = 0; j < 4; ++j)
                        ctxA[i][j] += pv[i].x * vv[j].x + pv[i].y * vv[j].y +
                                      pv[i].z * vv[j].z + pv[i].w * vv[j].w;
            }
            __syncthreads();
        } else {
            // strictly-upper tile: zero-fill (d_out is poisoned)
            const float4 z = {0.0f, 0.0f, 0.0f, 0.0f};
#pragma unroll
            for (int p = 0; p < 4; ++p) {
                const int q = qt * 64 + lr + p * 16;
                *(float4*)&attnBH[(size_t)q * S_ + jt * 64 + lc4] = z;
            }
        }
    }

    // write ctx in [B,S,H*HD] layout for the proj GEMM
#pragma unroll
    for (int i = 0; i < 4; ++i) {
        const int q = qt * 64 + ty + 16 * i;
#pragma unroll
        for (int j = 0; j < 4; ++j)
            ctxOut[((size_t)(b * S_ + q)) * D_ + h * HD_ + tx + 16 * j] = ctxA[i][j];
    }
}

extern "C" void kernel_launch(void* const* d_in, const int* in_sizes, int n_in,
                              void* d_out, int out_size, void* d_ws, size_t ws_size,
                              hipStream_t stream) {
    const float* hidden = (const float*)d_in[0];
    const float* mask   = (const float*)d_in[1];
    const float* w_attn = (const float*)d_in[2];
    const float* b_attn = (const float*)d_in[3];
    const float* w_proj = (const float*)d_in[4];
    const float* b_proj = (const float*)d_in[5];

    float* out = (float*)d_out;                       // [2,2048,1024]
    float* attnOut = out + (size_t)2 * S_ * D_;       // [2,16,2048,2048]

    float* ws  = (float*)d_ws;
    const size_t qkvSz = (size_t)2 * H_ * S_ * HD_;   // 4,194,304 floats
    float* qw  = ws;
    float* kw  = ws + qkvSz;
    float* vw  = ws + 2 * qkvSz;
    float* ctx = ws + 3 * qkvSz;

    dim3 blk(256);
    // qkv = hidden @ w_attn + b_attn, scattered into q/k/v heads
    gemm128<<<dim3(3 * D_ / 128, 2 * S_ / 128), blk, 0, stream>>>(
        hidden, w_attn, b_attn, nullptr, qw, kw, vw, 2 * S_, 3 * D_, D_, 1);
    // attention
    attn_kernel<<<dim3(2 * H_ * (S_ / 64)), blk, 0, stream>>>(
        qw, kw, vw, mask, attnOut, ctx);
    // out = ctx @ w_proj + b_proj
    gemm128<<<dim3(D_ / 128, 2 * S_ / 128), blk, 0, stream>>>(
        ctx, w_proj, b_proj, out, nullptr, nullptr, nullptr, 2 * S_, D_, D_, 0);
}

// Round 2
// 754.456 us; speedup vs baseline: 2.6706x; 2.6706x over previous
//
#include <hip/hip_runtime.h>

#define S_ 2048
#define D_ 1024
#define H_ 16
#define HD_ 64

typedef __attribute__((ext_vector_type(8))) short short8;
typedef __attribute__((ext_vector_type(4))) float floatx4;

#define MFMA16(a, b, c) __builtin_amdgcn_mfma_f32_16x16x32_bf16(a, b, c, 0, 0, 0)

__device__ inline unsigned short f2bf(float f) {
    union { float f; unsigned int u; } v; v.f = f;
    unsigned int r = v.u + 0x7FFFu + ((v.u >> 16) & 1u);  // RNE
    return (unsigned short)(r >> 16);
}

// ---------------- elementwise fp32 -> bf16 cast ----------------
__global__ __launch_bounds__(256) void cast_bf16(const float* __restrict__ in,
                                                 unsigned short* __restrict__ out, int n4) {
    int i = blockIdx.x * 256 + threadIdx.x;
    if (i < n4) {
        float4 v = ((const float4*)in)[i];
        ushort4 o;
        o.x = f2bf(v.x); o.y = f2bf(v.y); o.z = f2bf(v.z); o.w = f2bf(v.w);
        ((ushort4*)out)[i] = o;
    }
}

// ---------------- W [K][N] fp32 -> W^T [N][K] bf16 (64x64 LDS tiles) ----------------
__global__ __launch_bounds__(256) void transpose_cast(const float* __restrict__ W,
                                                      unsigned short* __restrict__ WT,
                                                      int K, int N) {
    __shared__ float tb[64][65];
    const int t = threadIdx.x;
    const int tr = t >> 4, tc = t & 15;
    const int n0 = blockIdx.x * 64, k0 = blockIdx.y * 64;
#pragma unroll
    for (int p = 0; p < 4; ++p) {
        const int r = p * 16 + tr;
        const float4 v = *(const float4*)&W[(size_t)(k0 + r) * N + n0 + tc * 4];
        tb[r][tc * 4 + 0] = v.x; tb[r][tc * 4 + 1] = v.y;
        tb[r][tc * 4 + 2] = v.z; tb[r][tc * 4 + 3] = v.w;
    }
    __syncthreads();
#pragma unroll
    for (int p = 0; p < 4; ++p) {
        const int rn = p * 16 + tr;
        ushort4 o;
        o.x = f2bf(tb[tc * 4 + 0][rn]); o.y = f2bf(tb[tc * 4 + 1][rn]);
        o.z = f2bf(tb[tc * 4 + 2][rn]); o.w = f2bf(tb[tc * 4 + 3][rn]);
        *(ushort4*)&WT[(size_t)(n0 + rn) * K + k0 + tc * 4] = o;
    }
}

// ---------------- bf16 MFMA GEMM: C[M][N] = A[M][K] * Bt[N][K]^T + bias ----------------
// 128x128 tile, BK=32, 4 waves (2x2), 16 mfma_16x16x32 per K-step.
// mode 0: fp32 store to outp.  mode 1: scatter bf16 -> q/k [B,H,S,HD], v^T [B,H,HD,S].
__global__ __launch_bounds__(256) void gemm_bt(
    const unsigned short* __restrict__ A, const unsigned short* __restrict__ Bt,
    const float* __restrict__ bias, float* __restrict__ outp,
    unsigned short* __restrict__ qw, unsigned short* __restrict__ kw,
    unsigned short* __restrict__ vtw, int M, int N, int K, int mode)
{
    __shared__ unsigned short As[128 * 32];
    __shared__ unsigned short Bs[128 * 32];

    const int tid = threadIdx.x;
    const int w = tid >> 6, lane = tid & 63;
    const int l15 = lane & 15, qd = lane >> 4;
    const int wr = w >> 1, wc = w & 1;
    const int row0 = blockIdx.y * 128, col0 = blockIdx.x * 128;

    floatx4 acc[4][4];
#pragma unroll
    for (int i = 0; i < 4; ++i)
#pragma unroll
        for (int j = 0; j < 4; ++j) acc[i][j] = (floatx4){0.f, 0.f, 0.f, 0.f};

    for (int k0 = 0; k0 < K; k0 += 32) {
        __syncthreads();
#pragma unroll
        for (int p = 0; p < 2; ++p) {
            const int c = p * 256 + tid;
            const int row = c >> 2, part = c & 3;
            *(uint4*)&As[row * 32 + part * 8] =
                *(const uint4*)&A[(size_t)(row0 + row) * K + k0 + part * 8];
            *(uint4*)&Bs[row * 32 + part * 8] =
                *(const uint4*)&Bt[(size_t)(col0 + row) * K + k0 + part * 8];
        }
        __syncthreads();
        short8 af[4], bfr[4];
#pragma unroll
        for (int mi = 0; mi < 4; ++mi)
            af[mi] = *(const short8*)&As[(wr * 64 + mi * 16 + l15) * 32 + qd * 8];
#pragma unroll
        for (int ni = 0; ni < 4; ++ni)
            bfr[ni] = *(const short8*)&Bs[(wc * 64 + ni * 16 + l15) * 32 + qd * 8];
#pragma unroll
        for (int mi = 0; mi < 4; ++mi)
#pragma unroll
            for (int ni = 0; ni < 4; ++ni)
                acc[mi][ni] = MFMA16(af[mi], bfr[ni], acc[mi][ni]);
    }

#pragma unroll
    for (int mi = 0; mi < 4; ++mi)
#pragma unroll
        for (int ni = 0; ni < 4; ++ni) {
            const int col = col0 + wc * 64 + ni * 16 + l15;
            const float bv = bias[col];
#pragma unroll
            for (int r = 0; r < 4; ++r) {
                const int row = row0 + wr * 64 + mi * 16 + qd * 4 + r;
                const float v = acc[mi][ni][r] + bv;
                if (mode == 0) {
                    outp[(size_t)row * N + col] = v;
                } else {
                    const int region = col >> 10;
                    const int hh = (col >> 6) & 15;
                    const int dd = col & 63;
                    const int bb = row >> 11;
                    const int ss = row & 2047;
                    const unsigned short bvv = f2bf(v);
                    if (region == 0)
                        qw[((size_t)(bb * 16 + hh) * 2048 + ss) * 64 + dd] = bvv;
                    else if (region == 1)
                        kw[((size_t)(bb * 16 + hh) * 2048 + ss) * 64 + dd] = bvv;
                    else
                        vtw[((size_t)(bb * 16 + hh) * 64 + dd) * 2048 + ss] = bvv;
                }
            }
        }
}

// ---------------- MFMA attention: block per (b,h, 64-row q tile), two-pass ----------------
__global__ __launch_bounds__(256) void attn_mfma(
    const unsigned short* __restrict__ qg, const unsigned short* __restrict__ kg,
    const unsigned short* __restrict__ vtg, const float* __restrict__ mask,
    float* __restrict__ attnOut, unsigned short* __restrict__ ctxOut)
{
    __shared__ unsigned short Qs[64 * 72];
    __shared__ unsigned short Ks[64 * 72];
    __shared__ unsigned short Vt[64 * 72];
    __shared__ unsigned short Ps[64 * 80];
    __shared__ float maskS[64];

    const int tid = threadIdx.x;
    const int w = tid >> 6, lane = tid & 63;
    const int l15 = lane & 15, qd = lane >> 4;
    const int x = blockIdx.x;
    const int bh = x & 31;
    const int qt = 31 - (x >> 5);      // heavy tiles dispatch first
    const int b = bh >> 4, h = bh & 15;
    const size_t base = (size_t)bh * (S_ * HD_);

    // stage Q tile (8 KB)
#pragma unroll
    for (int p = 0; p < 2; ++p) {
        const int c = p * 256 + tid;
        const int row = c >> 3, part = c & 7;
        *(uint4*)&Qs[row * 72 + part * 8] =
            *(const uint4*)&qg[base + (size_t)(qt * 64 + row) * 64 + part * 8];
    }
    __syncthreads();
    const short8 aq0 = *(const short8*)&Qs[(w * 16 + l15) * 72 + 0 + qd * 8];
    const short8 aq1 = *(const short8*)&Qs[(w * 16 + l15) * 72 + 32 + qd * 8];

    const int qrow_base = qt * 64 + w * 16 + qd * 4;
    float m_i[4], l_i[4], rl[4];
#pragma unroll
    for (int r = 0; r < 4; ++r) { m_i[r] = -3e38f; l_i[r] = 0.f; }

    // ---- pass 1: softmax stats ----
    for (int jt = 0; jt <= qt; ++jt) {
        __syncthreads();
#pragma unroll
        for (int p = 0; p < 2; ++p) {
            const int c = p * 256 + tid;
            const int row = c >> 3, part = c & 7;
            *(uint4*)&Ks[row * 72 + part * 8] =
                *(const uint4*)&kg[base + (size_t)(jt * 64 + row) * 64 + part * 8];
        }
        if (tid < 64) maskS[tid] = mask[b * S_ + jt * 64 + tid];
        __syncthreads();

        float sv[4][4];
#pragma unroll
        for (int ni = 0; ni < 4; ++ni) {
            const short8 bk0 = *(const short8*)&Ks[(ni * 16 + l15) * 72 + 0 + qd * 8];
            const short8 bk1 = *(const short8*)&Ks[(ni * 16 + l15) * 72 + 32 + qd * 8];
            floatx4 s = {0.f, 0.f, 0.f, 0.f};
            s = MFMA16(aq0, bk0, s);
            s = MFMA16(aq1, bk1, s);
#pragma unroll
            for (int r = 0; r < 4; ++r) sv[ni][r] = s[r] * 0.125f;
        }
#pragma unroll
        for (int r = 0; r < 4; ++r) {
            const int qrow = qrow_base + r;
            float svr[4], tm = -3e38f;
#pragma unroll
            for (int ni = 0; ni < 4; ++ni) {
                const int col = jt * 64 + ni * 16 + l15;
                const bool ok = (col <= qrow) && (maskS[ni * 16 + l15] == 1.0f);
                svr[ni] = ok ? sv[ni][r] : -3e38f;
                tm = fmaxf(tm, svr[ni]);
            }
            if (tm > -1e37f) {
                const float mn = fmaxf(m_i[r], tm);
                const float sum = __expf(svr[0] - mn) + __expf(svr[1] - mn) +
                                  __expf(svr[2] - mn) + __expf(svr[3] - mn);
                l_i[r] = l_i[r] * __expf(m_i[r] - mn) + sum;
                m_i[r] = mn;
            }
        }
    }

    // butterfly reduce over the 16 lanes sharing each row
#pragma unroll
    for (int r = 0; r < 4; ++r) {
        float m = m_i[r], l = l_i[r];
#pragma unroll
        for (int off = 1; off < 16; off <<= 1) {
            const float mo = __shfl_xor(m, off);
            const float lo = __shfl_xor(l, off);
            const float mn = fmaxf(m, mo);
            l = l * __expf(m - mn) + lo * __expf(mo - mn);
            m = mn;
        }
        m_i[r] = m;
        rl[r] = 1.0f / l;
    }

    // ---- pass 2: attn write + ctx ----
    floatx4 ctxa[4];
#pragma unroll
    for (int ni = 0; ni < 4; ++ni) ctxa[ni] = (floatx4){0.f, 0.f, 0.f, 0.f};
    float* attnBH = attnOut + (size_t)bh * S_ * S_;

    for (int jt = 0; jt < 32; ++jt) {
        if (jt <= qt) {
            __syncthreads();
#pragma unroll
            for (int p = 0; p < 2; ++p) {
                const int c = p * 256 + tid;
                const int row = c >> 3, part = c & 7;
                *(uint4*)&Ks[row * 72 + part * 8] =
                    *(const uint4*)&kg[base + (size_t)(jt * 64 + row) * 64 + part * 8];
                *(uint4*)&Vt[row * 72 + part * 8] =
                    *(const uint4*)&vtg[base + (size_t)row * S_ + jt * 64 + part * 8];
            }
            if (tid < 64) maskS[tid] = mask[b * S_ + jt * 64 + tid];
            __syncthreads();

            float sv[4][4];
#pragma unroll
            for (int ni = 0; ni < 4; ++ni) {
                const short8 bk0 = *(const short8*)&Ks[(ni * 16 + l15) * 72 + 0 + qd * 8];
                const short8 bk1 = *(const short8*)&Ks[(ni * 16 + l15) * 72 + 32 + qd * 8];
                floatx4 s = {0.f, 0.f, 0.f, 0.f};
                s = MFMA16(aq0, bk0, s);
                s = MFMA16(aq1, bk1, s);
#pragma unroll
                for (int r = 0; r < 4; ++r) sv[ni][r] = s[r] * 0.125f;
            }
#pragma unroll
            for (int ni = 0; ni < 4; ++ni) {
#pragma unroll
                for (int r = 0; r < 4; ++r) {
                    const int qrow = qrow_base + r;
                    const int col = jt * 64 + ni * 16 + l15;
                    const bool ok = (col <= qrow) && (maskS[ni * 16 + l15] == 1.0f);
                    const float p = ok ? __expf(sv[ni][r] - m_i[r]) * rl[r] : 0.0f;
                    attnBH[(size_t)qrow * S_ + col] = p;
                    Ps[(w * 16 + qd * 4 + r) * 80 + ni * 16 + l15] = f2bf(p);
                }
            }
            __syncthreads();
#pragma unroll
            for (int kk = 0; kk < 2; ++kk) {
                const short8 ap = *(const short8*)&Ps[(w * 16 + l15) * 80 + kk * 32 + qd * 8];
#pragma unroll
                for (int ni = 0; ni < 4; ++ni) {
                    const short8 bv = *(const short8*)&Vt[(ni * 16 + l15) * 72 + kk * 32 + qd * 8];
                    ctxa[ni] = MFMA16(ap, bv, ctxa[ni]);
                }
            }
        } else {
            const float4 z = {0.f, 0.f, 0.f, 0.f};
#pragma unroll
            for (int p = 0; p < 4; ++p) {
                const int c = p * 256 + tid;
                const int row = c >> 4, part = c & 15;
                *(float4*)&attnBH[(size_t)(qt * 64 + row) * S_ + jt * 64 + part * 4] = z;
            }
        }
    }

    // ctx -> bf16 [B,S,D]
#pragma unroll
    for (int ni = 0; ni < 4; ++ni)
#pragma unroll
        for (int r = 0; r < 4; ++r) {
            const int qrow = qrow_base + r;
            ctxOut[((size_t)(b * S_ + qrow)) * D_ + h * 64 + ni * 16 + l15] =
                f2bf(ctxa[ni][r]);
        }
}

extern "C" void kernel_launch(void* const* d_in, const int* in_sizes, int n_in,
                              void* d_out, int out_size, void* d_ws, size_t ws_size,
                              hipStream_t stream) {
    const float* hidden = (const float*)d_in[0];
    const float* mask   = (const float*)d_in[1];
    const float* w_attn = (const float*)d_in[2];
    const float* b_attn = (const float*)d_in[3];
    const float* w_proj = (const float*)d_in[4];
    const float* b_proj = (const float*)d_in[5];

    float* out = (float*)d_out;
    float* attnOut = out + (size_t)2 * S_ * D_;

    unsigned short* ws = (unsigned short*)d_ws;
    const size_t E = (size_t)2 * S_ * D_;       // 4,194,304
    unsigned short* Xb   = ws;                  // [2*S, D]
    unsigned short* WaT  = Xb + E;              // [3D, D]
    unsigned short* WpT  = WaT + (size_t)3 * D_ * D_;  // [D, D]
    unsigned short* qw   = WpT + (size_t)D_ * D_;      // [B,H,S,HD]
    unsigned short* kw   = qw + E;
    unsigned short* vtw  = kw + E;              // [B,H,HD,S]
    unsigned short* ctxb = vtw + E;             // [2*S, D]

    dim3 blk(256);
    cast_bf16<<<dim3((int)(E / 4 / 256)), blk, 0, stream>>>(hidden, Xb, (int)(E / 4));
    transpose_cast<<<dim3(3 * D_ / 64, D_ / 64), blk, 0, stream>>>(w_attn, WaT, D_, 3 * D_);
    transpose_cast<<<dim3(D_ / 64, D_ / 64), blk, 0, stream>>>(w_proj, WpT, D_, D_);

    gemm_bt<<<dim3(3 * D_ / 128, 2 * S_ / 128), blk, 0, stream>>>(
        Xb, WaT, b_attn, nullptr, qw, kw, vtw, 2 * S_, 3 * D_, D_, 1);

    attn_mfma<<<dim3(2 * H_ * (S_ / 64)), blk, 0, stream>>>(
        qw, kw, vtw, mask, attnOut, ctxb);

    gemm_bt<<<dim3(D_ / 128, 2 * S_ / 128), blk, 0, stream>>>(
        ctxb, WpT, b_proj, out, nullptr, nullptr, nullptr, 2 * S_, D_, D_, 0);
}